// Round 2
// baseline (878.805 us; speedup 1.0000x reference)
//
#include <hip/hip_runtime.h>

typedef __bf16  bf16x8 __attribute__((ext_vector_type(8)));
typedef float   f32x4  __attribute__((ext_vector_type(4)));

union ABCast { uint4 u; bf16x8 f; };

__device__ __forceinline__ unsigned short f2bf(float x) {
  unsigned u = __builtin_bit_cast(unsigned, x);
  u += 0x7FFFu + ((u >> 16) & 1u);          // round-to-nearest-even
  return (unsigned short)(u >> 16);
}

#define IMG_W  512
#define IMG_HW (512 * 512)
#define TILE_R 16
#define TILE_C 32
#define TIN_H  18
#define TIN_W  34
// LDS pixel layout: 64 B/pixel (32 ch bf16), 4x 16B channel-groups XOR-swizzled:
//   group g of pixel p lives at ushort offset p*32 + (g ^ ((p>>1)&3))*8.
// Every 8 consecutive pixels x any cg cover all 8 bank-quads once -> conflict-free
// for both staging 16B writes and main-loop ds_read_b128, with zero padding.
// 612 px * 64 B = 39168 B  ->  4 blocks/CU (was 48960 B -> 3 blocks/CU).
#define SWZ(p, g) (((p) << 5) + (((g) ^ (((p) >> 1) & 3)) << 3))

// Pre-pack OIHW fp32 weights into per-lane B-fragment order for mfma_f32_16x16x32_bf16:
// B[k=c][n=oc_local], lane = ((c>>3)<<4) | (oc&15), j = c&7, per (tap, oc-half).
__global__ void pack_weights(const float* __restrict__ w, unsigned short* __restrict__ wsb) {
  int f = blockIdx.x * 256 + threadIdx.x;
  if (f < 9216) {
    int kw = f % 3, kh = (f / 3) % 3, c = (f / 9) % 32, oc = f / 288;
    int tap = kh * 3 + kw, nh = oc >> 4;
    int lane = ((c >> 3) << 4) | (oc & 15);
    int j = c & 7;
    wsb[(((tap * 2 + nh) * 64) + lane) * 8 + j] = f2bf(w[f]);
  }
}

// Block: 256 threads = 4 waves; computes 16 rows x 32 cols x 32 oc.
// wave: nh = oc-half (0/1), rq = row-half (0/1): 8 rows x 32 cols x 16 oc
//       = 16 M-frags (8 rows x 2 col-halves) x 1 N-frag, 9 taps.
__global__ __launch_bounds__(256, 4)
void conv3x3(const float* __restrict__ x, const float* __restrict__ bias,
             const unsigned short* __restrict__ wsb, float* __restrict__ out) {
  __shared__ unsigned short smem[TIN_H * TIN_W * 32]; // 612 px * 64 B = 39168 B

  const int b    = blockIdx.x;
  const int n    = b & 7;        // image per XCD (round-robin heuristic)
  const int t    = b >> 3;
  const int tr   = t >> 4;       // 0..31 row tile
  const int tc   = t & 15;       // 0..15 col tile
  const int tid  = threadIdx.x;
  const int lane = tid & 63;
  const int wave = tid >> 6;
  const int nh   = wave & 1;
  const int rq   = wave >> 1;

  const float* xn = x + (size_t)n * 32 * IMG_HW;

  // B fragments: 9 coalesced 16B loads from pre-packed ws (L2-warm), kept in VGPRs.
  bf16x8 bfrag[9];
  {
    const uint4* wp = (const uint4*)wsb;
    #pragma unroll
    for (int tap = 0; tap < 9; ++tap) {
      ABCast cv; cv.u = wp[(tap * 2 + nh) * 64 + lane];
      bfrag[tap] = cv.f;
    }
  }
  const float bs = bias[nh * 16 + (lane & 15)];

  // ---- Stage input tile (18x34 px, 32 ch) fp32 -> bf16 into LDS (swizzled) ----
  const int r0 = tr * TILE_R - 1;
  const int c0 = tc * TILE_C - 1;
  #pragma unroll
  for (int it = 0; it < 3; ++it) {
    int p = tid + it * 256;
    if (p < TIN_H * TIN_W) {
      int pr = p / TIN_W, pc = p - pr * TIN_W;
      int gr = r0 + pr,  gc = c0 + pc;
      float v[32];
      if ((unsigned)gr < 512u && (unsigned)gc < 512u) {
        const float* src = xn + (size_t)gr * IMG_W + gc;
        #pragma unroll
        for (int c = 0; c < 32; ++c) v[c] = src[(size_t)c * IMG_HW];
      } else {
        #pragma unroll
        for (int c = 0; c < 32; ++c) v[c] = 0.0f;
      }
      #pragma unroll
      for (int g = 0; g < 4; ++g) {
        uint4 wv;
        wv.x = (unsigned)f2bf(v[8 * g + 0]) | ((unsigned)f2bf(v[8 * g + 1]) << 16);
        wv.y = (unsigned)f2bf(v[8 * g + 2]) | ((unsigned)f2bf(v[8 * g + 3]) << 16);
        wv.z = (unsigned)f2bf(v[8 * g + 4]) | ((unsigned)f2bf(v[8 * g + 5]) << 16);
        wv.w = (unsigned)f2bf(v[8 * g + 6]) | ((unsigned)f2bf(v[8 * g + 7]) << 16);
        *(uint4*)(smem + SWZ(p, g)) = wv;
      }
    }
  }
  __syncthreads();

  // ---- MFMA main loop ----
  f32x4 acc[16];
  #pragma unroll
  for (int i = 0; i < 16; ++i) acc[i] = (f32x4){0.f, 0.f, 0.f, 0.f};

  // A-frag: lane reads A[m=lane&15][k=cg*8+j], pixel = pxbase + m, cg = lane>>4.
  const int m = lane & 15, cg = lane >> 4;

  #pragma unroll
  for (int kh = 0; kh < 3; ++kh) {
    #pragma unroll
    for (int kw = 0; kw < 3; ++kw) {
      const bf16x8 bf = bfrag[kh * 3 + kw];
      #pragma unroll
      for (int i = 0; i < 8; ++i) {
        #pragma unroll
        for (int ch = 0; ch < 2; ++ch) {
          int p = (rq * 8 + i + kh) * TIN_W + ch * 16 + kw + m;
          ABCast cv; cv.u = *(const uint4*)(smem + SWZ(p, cg));
          acc[i * 2 + ch] =
              __builtin_amdgcn_mfma_f32_16x16x32_bf16(cv.f, bf, acc[i * 2 + ch], 0, 0, 0);
        }
      }
    }
  }

  // ---- Epilogue: transpose through LDS (reuse smem), then full-line stores ----
  // Pair p = rg*32 + oc, rg in 0..7 (row group), oc in 0..31; each pair owns a
  // 32-float (128B) row segment stored as 8 xor-swizzled 16B chunks:
  //   chunk c lives at slot (c ^ (p&7))  -> both phases hit the LDS floor.
  float* sf = (float*)smem;               // need 8192 floats = 32 KB per pass
  const int ocl = lane & 15, q = lane >> 4;
  float* outn = out + (size_t)n * 32 * IMG_HW;
  __syncthreads();                        // all waves done reading input tile

  #pragma unroll
  for (int P = 0; P < 2; ++P) {
    // Write phase: all 4 waves write acc i = P*4..P*4+3 (rows rq*8 + P*4 + ii).
    #pragma unroll
    for (int ii = 0; ii < 4; ++ii) {
      int i = P * 4 + ii;
      int p = (rq * 4 + ii) * 32 + nh * 16 + ocl;
      #pragma unroll
      for (int ch = 0; ch < 2; ++ch) {
        int slot = (ch * 4 + q) ^ (p & 7);
        f32x4 v = acc[i * 2 + ch];
        v += bs;
        *(f32x4*)(sf + p * 32 + slot * 4) = v;
      }
    }
    __syncthreads();
    // Read phase: 8 consecutive lanes cover one (oc,row) 128B segment.
    {
      const int s = tid >> 3, off = tid & 7;   // s = oc (0..31), off = col chunk
      #pragma unroll
      for (int it = 0; it < 8; ++it) {
        int p = it * 32 + s;                   // rg = it, oc = s
        f32x4 v = *(const f32x4*)(sf + p * 32 + ((off ^ (p & 7)) * 4));
        int row = tr * TILE_R + (it >> 2) * 8 + P * 4 + (it & 3);
        *(f32x4*)(outn + (size_t)s * IMG_HW + (size_t)row * IMG_W
                  + tc * TILE_C + off * 4) = v;
      }
    }
    if (P == 0) __syncthreads();               // pass-0 readers done before pass-1 writes
  }
}

extern "C" void kernel_launch(void* const* d_in, const int* in_sizes, int n_in,
                              void* d_out, int out_size, void* d_ws, size_t ws_size,
                              hipStream_t stream) {
  const float* x    = (const float*)d_in[0];
  const float* w    = (const float*)d_in[1];
  const float* bias = (const float*)d_in[2];
  float* out = (float*)d_out;
  unsigned short* wsb = (unsigned short*)d_ws;

  hipLaunchKernelGGL(pack_weights, dim3(36), dim3(256), 0, stream, w, wsb);
  hipLaunchKernelGGL(conv3x3, dim3(8 * 32 * 16), dim3(256), 0, stream, x, bias, wsb, out);
}

// Round 3
// 864.976 us; speedup vs baseline: 1.0160x; 1.0160x over previous
//
#include <hip/hip_runtime.h>

typedef __bf16  bf16x8 __attribute__((ext_vector_type(8)));
typedef float   f32x4  __attribute__((ext_vector_type(4)));

union ABCast { uint4 u; bf16x8 f; };

__device__ __forceinline__ unsigned short f2bf(float x) {
  unsigned u = __builtin_bit_cast(unsigned, x);
  u += 0x7FFFu + ((u >> 16) & 1u);          // round-to-nearest-even
  return (unsigned short)(u >> 16);
}

#define IMG_W  512
#define IMG_HW (512 * 512)
#define TILE_R 16
#define TILE_C 32
#define TIN_H  18
#define TIN_W  34
// LDS pixel layout: 64 B/pixel (32 ch bf16), 4x 16B channel-groups XOR-swizzled:
//   group g of pixel p lives at ushort offset p*32 + (g ^ ((p>>1)&3))*8.
// Conflict-free for staging writes and ds_read_b128 (verified: bank-conflict ctr = 0).
// 612 px * 64 B = 39168 B  ->  4 blocks/CU.
#define SWZ(p, g) (((p) << 5) + (((g) ^ (((p) >> 1) & 3)) << 3))

// Pre-pack OIHW fp32 weights into per-lane B-fragment order for mfma_f32_16x16x32_bf16:
// B[k=c][n=oc_local], lane = ((c>>3)<<4) | (oc&15), j = c&7, per (tap, oc-half).
__global__ void pack_weights(const float* __restrict__ w, unsigned short* __restrict__ wsb) {
  int f = blockIdx.x * 256 + threadIdx.x;
  if (f < 9216) {
    int kw = f % 3, kh = (f / 3) % 3, c = (f / 9) % 32, oc = f / 288;
    int tap = kh * 3 + kw, nh = oc >> 4;
    int lane = ((c >> 3) << 4) | (oc & 15);
    int j = c & 7;
    wsb[(((tap * 2 + nh) * 64) + lane) * 8 + j] = f2bf(w[f]);
  }
}

// Block: 256 threads = 4 waves; computes 16 rows x 32 cols x 32 oc.
// wave: nh = oc-half (0/1), rq = row-half (0/1): 8 rows x 32 cols x 16 oc.
// Output is write-once / zero-reuse: stores use __builtin_nontemporal_store (nt)
// to bypass L2 write-allocate -- removes the ~1x-output extra FETCH and the
// output-churn L2 pollution that thrashed input halo reuse at 4 blocks/CU.
__global__ __launch_bounds__(256, 4)
void conv3x3(const float* __restrict__ x, const float* __restrict__ bias,
             const unsigned short* __restrict__ wsb, float* __restrict__ out) {
  __shared__ unsigned short smem[TIN_H * TIN_W * 32]; // 612 px * 64 B = 39168 B

  const int b    = blockIdx.x;
  const int n    = b & 7;        // image per XCD (round-robin heuristic)
  const int t    = b >> 3;
  const int tr   = t >> 4;       // 0..31 row tile
  const int tc   = t & 15;       // 0..15 col tile
  const int tid  = threadIdx.x;
  const int lane = tid & 63;
  const int wave = tid >> 6;
  const int nh   = wave & 1;
  const int rq   = wave >> 1;

  const float* xn = x + (size_t)n * 32 * IMG_HW;

  // B fragments: 9 coalesced 16B loads from pre-packed ws (L2-warm), kept in VGPRs.
  bf16x8 bfrag[9];
  {
    const uint4* wp = (const uint4*)wsb;
    #pragma unroll
    for (int tap = 0; tap < 9; ++tap) {
      ABCast cv; cv.u = wp[(tap * 2 + nh) * 64 + lane];
      bfrag[tap] = cv.f;
    }
  }
  const float bs = bias[nh * 16 + (lane & 15)];

  // ---- Stage input tile (18x34 px, 32 ch) fp32 -> bf16 into LDS (swizzled) ----
  const int r0 = tr * TILE_R - 1;
  const int c0 = tc * TILE_C - 1;
  #pragma unroll
  for (int it = 0; it < 3; ++it) {
    int p = tid + it * 256;
    if (p < TIN_H * TIN_W) {
      int pr = p / TIN_W, pc = p - pr * TIN_W;
      int gr = r0 + pr,  gc = c0 + pc;
      float v[32];
      if ((unsigned)gr < 512u && (unsigned)gc < 512u) {
        const float* src = xn + (size_t)gr * IMG_W + gc;
        #pragma unroll
        for (int c = 0; c < 32; ++c) v[c] = src[(size_t)c * IMG_HW];
      } else {
        #pragma unroll
        for (int c = 0; c < 32; ++c) v[c] = 0.0f;
      }
      #pragma unroll
      for (int g = 0; g < 4; ++g) {
        uint4 wv;
        wv.x = (unsigned)f2bf(v[8 * g + 0]) | ((unsigned)f2bf(v[8 * g + 1]) << 16);
        wv.y = (unsigned)f2bf(v[8 * g + 2]) | ((unsigned)f2bf(v[8 * g + 3]) << 16);
        wv.z = (unsigned)f2bf(v[8 * g + 4]) | ((unsigned)f2bf(v[8 * g + 5]) << 16);
        wv.w = (unsigned)f2bf(v[8 * g + 6]) | ((unsigned)f2bf(v[8 * g + 7]) << 16);
        *(uint4*)(smem + SWZ(p, g)) = wv;
      }
    }
  }
  __syncthreads();

  // ---- MFMA main loop ----
  f32x4 acc[16];
  #pragma unroll
  for (int i = 0; i < 16; ++i) acc[i] = (f32x4){0.f, 0.f, 0.f, 0.f};

  // A-frag: lane reads A[m=lane&15][k=cg*8+j], pixel = pxbase + m, cg = lane>>4.
  const int m = lane & 15, cg = lane >> 4;

  #pragma unroll
  for (int kh = 0; kh < 3; ++kh) {
    #pragma unroll
    for (int kw = 0; kw < 3; ++kw) {
      const bf16x8 bf = bfrag[kh * 3 + kw];
      #pragma unroll
      for (int i = 0; i < 8; ++i) {
        #pragma unroll
        for (int ch = 0; ch < 2; ++ch) {
          int p = (rq * 8 + i + kh) * TIN_W + ch * 16 + kw + m;
          ABCast cv; cv.u = *(const uint4*)(smem + SWZ(p, cg));
          acc[i * 2 + ch] =
              __builtin_amdgcn_mfma_f32_16x16x32_bf16(cv.f, bf, acc[i * 2 + ch], 0, 0, 0);
        }
      }
    }
  }

  // ---- Epilogue: transpose through LDS (reuse smem), then full-line NT stores ----
  float* sf = (float*)smem;               // need 8192 floats = 32 KB per pass
  const int ocl = lane & 15, q = lane >> 4;
  float* outn = out + (size_t)n * 32 * IMG_HW;
  __syncthreads();                        // all waves done reading input tile

  #pragma unroll
  for (int P = 0; P < 2; ++P) {
    // Write phase: all 4 waves write acc i = P*4..P*4+3 (rows rq*8 + P*4 + ii).
    #pragma unroll
    for (int ii = 0; ii < 4; ++ii) {
      int i = P * 4 + ii;
      int p = (rq * 4 + ii) * 32 + nh * 16 + ocl;
      #pragma unroll
      for (int ch = 0; ch < 2; ++ch) {
        int slot = (ch * 4 + q) ^ (p & 7);
        f32x4 v = acc[i * 2 + ch];
        v += bs;
        *(f32x4*)(sf + p * 32 + slot * 4) = v;
      }
    }
    __syncthreads();
    // Read phase: 8 consecutive lanes cover one (oc,row) 128B segment; nt store.
    {
      const int s = tid >> 3, off = tid & 7;   // s = oc (0..31), off = col chunk
      #pragma unroll
      for (int it = 0; it < 8; ++it) {
        int p = it * 32 + s;                   // rg = it, oc = s
        f32x4 v = *(const f32x4*)(sf + p * 32 + ((off ^ (p & 7)) * 4));
        int row = tr * TILE_R + (it >> 2) * 8 + P * 4 + (it & 3);
        __builtin_nontemporal_store(
            v, (f32x4*)(outn + (size_t)s * IMG_HW + (size_t)row * IMG_W
                        + tc * TILE_C + off * 4));
      }
    }
    if (P == 0) __syncthreads();               // pass-0 readers done before pass-1 writes
  }
}

extern "C" void kernel_launch(void* const* d_in, const int* in_sizes, int n_in,
                              void* d_out, int out_size, void* d_ws, size_t ws_size,
                              hipStream_t stream) {
  const float* x    = (const float*)d_in[0];
  const float* w    = (const float*)d_in[1];
  const float* bias = (const float*)d_in[2];
  float* out = (float*)d_out;
  unsigned short* wsb = (unsigned short*)d_ws;

  hipLaunchKernelGGL(pack_weights, dim3(36), dim3(256), 0, stream, w, wsb);
  hipLaunchKernelGGL(conv3x3, dim3(8 * 32 * 16), dim3(256), 0, stream, x, bias, wsb, out);
}